// Round 5
// baseline (184.818 us; speedup 1.0000x reference)
//
#include <hip/hip_runtime.h>
#include <math.h>

#define TPB 256
#define TPB_E 512
#define TPB_P 512

typedef unsigned short u16;
typedef unsigned int u32;
typedef __attribute__((ext_vector_type(8))) _Float16 f16x8;
typedef __attribute__((ext_vector_type(4))) float f32x4;

// ---------------- ws layout ----------------
#define BLOB_U16 524288
#define BASE_RC_F32 327680
#define BASE_AN_F32 1376256
#define RC1P_F32 1900544
#define AN1P_F32 2949120
#define WS_NEED_BASES ((size_t)1900544 * 4)  // ~7.6 MB
#define WS_NEED_PRE   ((size_t)3473408 * 4)  // ~13.9 MB
// blob-internal u16 offsets (hi[OK] then lo[OK]; lo unused for hi-only layers)
#define RC1F 0       // O=128, K=64  T=8 OK=8192  [2-term, fallback only]
#define AN1F 16384   // O=64,  K=64  T=4 OK=4096  [2-term, fallback only]
#define AN2F 24576   // O=128, K=64  T=8 OK=8192  [hi-only RNE]
#define RC2F 40960   // O=128, K=128 T=8 OK=16384 [hi-only RNE]
#define RC3F 73728   // O=128, K=128 T=8 OK=16384 [hi-only RNE]

#define ENC_BLOCKS 128
#define PREP_BLOCKS 208

__device__ __forceinline__ float h2f(u16 b) {
  return (float)__builtin_bit_cast(_Float16, b);
}
__device__ __forceinline__ u16 f2h_rne(float x) {
  return __builtin_bit_cast(u16, (_Float16)x);  // RNE
}
__device__ __forceinline__ void split_f16(float x, u16& hi, u16& lo) {
  _Float16 h = (_Float16)x;
  hi = __builtin_bit_cast(u16, h);
  lo = __builtin_bit_cast(u16, (_Float16)(x - (float)h));
}
__device__ __forceinline__ unsigned pack_f16(float v0, float v1) {
  auto h = __builtin_amdgcn_cvt_pkrtz(v0, v1);
  return __builtin_bit_cast(unsigned, h);
}
__device__ __forceinline__ void split4(const float4 v, uint2& H, uint2& L) {
  _Float16 h0 = (_Float16)v.x, h1 = (_Float16)v.y;
  _Float16 h2 = (_Float16)v.z, h3 = (_Float16)v.w;
  _Float16 l0 = (_Float16)(v.x - (float)h0), l1 = (_Float16)(v.y - (float)h1);
  _Float16 l2 = (_Float16)(v.z - (float)h2), l3 = (_Float16)(v.w - (float)h3);
  H.x = (u32)__builtin_bit_cast(u16, h0) | ((u32)__builtin_bit_cast(u16, h1) << 16);
  H.y = (u32)__builtin_bit_cast(u16, h2) | ((u32)__builtin_bit_cast(u16, h3) << 16);
  L.x = (u32)__builtin_bit_cast(u16, l0) | ((u32)__builtin_bit_cast(u16, l1) << 16);
  L.y = (u32)__builtin_bit_cast(u16, l2) | ((u32)__builtin_bit_cast(u16, l3) << 16);
}
__device__ __forceinline__ void ld4(float r[4], const float* p) {
  float4 v = *(const float4*)p;
  r[0] = v.x; r[1] = v.y; r[2] = v.z; r[3] = v.w;
}

// ---------------------------------------------------------------------------
// Weight prep into LDS A-fragments (hi/lo), enc kernel. For elem (o,k):
// idx = ((k>>5)*(O/16) + (o>>4))*512 + ((k>>3)&3)*128 + (o&15)*8 + (k&7)
// ---------------------------------------------------------------------------
template<int KDIM, int ODIM, int NT>
__device__ __forceinline__ void prep_w(u16* __restrict__ hi, u16* __restrict__ lo,
                                       const float* __restrict__ W, int tid) {
  constexpr int N = KDIM * ODIM / NT;
  constexpr int BATCH = (N < 16) ? N : 16;
  constexpr int OSH = (ODIM == 128) ? 7 : 6;
#pragma unroll
  for (int base = 0; base < N; base += BATCH) {
    float v[BATCH];
#pragma unroll
    for (int i = 0; i < BATCH; ++i) v[i] = W[(base + i) * NT + tid];
#pragma unroll
    for (int i = 0; i < BATCH; ++i) {
      const int e = (base + i) * NT + tid;
      const int k = e >> OSH, o = e & (ODIM - 1);
      const int idx = ((k >> 5) * (ODIM >> 4) + (o >> 4)) * 512 +
                      ((k >> 3) & 3) * 128 + (o & 15) * 8 + (k & 7);
      const float x = v[i];
      const _Float16 h = (_Float16)x;
      hi[idx] = __builtin_bit_cast(u16, h);
      lo[idx] = __builtin_bit_cast(u16, (_Float16)(x - (float)h));
    }
  }
}

// 3-term split MFMA: acc += (Whi+Wlo)@(Xhi+Xlo) dropping Wlo*Xlo (~2^-22 err)
template<int MT, int NCHUNK, int RSG, int TILES>
__device__ __forceinline__ void run3(f32x4 (&acc)[MT][4],
    const u16* __restrict__ wHi, const u16* __restrict__ wLo,
    const u16* __restrict__ bHi, const u16* __restrict__ bLo,
    int tg0, int quad, int l15) {
  const int lane = quad * 16 + l15;
#pragma unroll
  for (int c = 0; c < NCHUNK; ++c) {
    f16x8 Ah[MT], Al[MT];
#pragma unroll
    for (int t = 0; t < MT; ++t) {
      const int off = ((c * TILES + tg0 + t) * 64 + lane) * 8;
      Ah[t] = *(const f16x8*)(wHi + off);
      Al[t] = *(const f16x8*)(wLo + off);
    }
    const int slot = (4 * c + quad) ^ (l15 & 7);
    f16x8 Bh[4], Bl[4];
#pragma unroll
    for (int s = 0; s < 4; ++s) {
      const int off = (16 * s + l15) * (RSG * 8) + slot * 8;
      Bh[s] = *(const f16x8*)(bHi + off);
      Bl[s] = *(const f16x8*)(bLo + off);
    }
#pragma unroll
    for (int t = 0; t < MT; ++t)
#pragma unroll
      for (int s = 0; s < 4; ++s) {
        f32x4 a = acc[t][s];
        a = __builtin_amdgcn_mfma_f32_16x16x32_f16(Ah[t], Bh[s], a, 0, 0, 0);
        a = __builtin_amdgcn_mfma_f32_16x16x32_f16(Al[t], Bh[s], a, 0, 0, 0);
        a = __builtin_amdgcn_mfma_f32_16x16x32_f16(Ah[t], Bl[s], a, 0, 0, 0);
        acc[t][s] = a;
      }
  }
}

template<int MT, int RSG>
__device__ __forceinline__ void store_hl(const f32x4 (&acc)[MT][4],
    u16* __restrict__ dH, u16* __restrict__ dL, int o0, int quad, int l15) {
#pragma unroll
  for (int t = 0; t < MT; ++t) {
    const int ob = o0 + 16 * t + quad * 4;
    const int slot = (ob >> 3) ^ (l15 & 7);
    const int e = ob & 7;
#pragma unroll
    for (int s = 0; s < 4; ++s) {
      const int j = 16 * s + l15;
      float4 v = make_float4(fmaxf(acc[t][s][0], 0.f), fmaxf(acc[t][s][1], 0.f),
                             fmaxf(acc[t][s][2], 0.f), fmaxf(acc[t][s][3], 0.f));
      uint2 H, L;
      split4(v, H, L);
      *(uint2*)&dH[j * (RSG * 8) + slot * 8 + e] = H;
      *(uint2*)&dL[j * (RSG * 8) + slot * 8 + e] = L;
    }
  }
}

template<int MT>
__device__ __forceinline__ void initb(f32x4 (&acc)[MT][4], const float* bias,
                                      int o0, int quad) {
#pragma unroll
  for (int t = 0; t < MT; ++t) {
    float bb[4];
    ld4(bb, &bias[o0 + 16 * t + quad * 4]);
#pragma unroll
    for (int s = 0; s < 4; ++s) {
      f32x4 a;
#pragma unroll
      for (int r = 0; r < 4; ++r) a[r] = bb[r];
      acc[t][s] = a;
    }
  }
}
template<int MT>
__device__ __forceinline__ void zeroa(f32x4 (&acc)[MT][4]) {
#pragma unroll
  for (int t = 0; t < MT; ++t)
#pragma unroll
    for (int s = 0; s < 4; ++s) {
      f32x4 a;
#pragma unroll
      for (int r = 0; r < 4; ++r) a[r] = 0.f;
      acc[t][s] = a;
    }
}

// ---------------------------------------------------------------------------
// Kernel A1: MFMA encoder, one block per b, 512 threads. (Unchanged from R4.)
// ---------------------------------------------------------------------------
__global__ __launch_bounds__(TPB_E, 1) void enc_kernel(
    const float* __restrict__ s_in,
    const float* __restrict__ se_w1, const float* __restrict__ se_b1,
    const float* __restrict__ se_w2, const float* __restrict__ se_b2,
    const float* __restrict__ sd_w1, const float* __restrict__ sd_b1,
    const float* __restrict__ sd_w2, const float* __restrict__ sd_b2,
    const float* __restrict__ rc_w1, const float* __restrict__ rc_b1,
    const float* __restrict__ an_w1, const float* __restrict__ an_b1,
    u16* __restrict__ hB,
    float* __restrict__ baseRcG, float* __restrict__ baseAnG,
    float* __restrict__ rc1pG, float* __restrict__ an1pG,
    int do_bases, int do_pre,
    float* __restrict__ out) {
  __shared__ __align__(16) u16 sW[32768];
  __shared__ __align__(16) u16 sB0h[4096], sB0l[4096];
  __shared__ __align__(16) u16 sB1h[4096], sB1l[4096];
  __shared__ __align__(16) u16 sB2h[8192], sB2l[8192];
  __shared__ float sb[576];
  __shared__ float sRed[128];

  const int tid = threadIdx.x;
  const int w = tid >> 6, lane = tid & 63;
  const int quad = lane >> 4, l15 = lane & 15;
  const int b = blockIdx.x;
  const int o0 = w * 16;
  const bool act4 = (w < 4);

  if (tid < 64) {
    sb[tid] = se_b1[tid]; sb[64 + tid] = se_b2[tid]; sb[512 + tid] = an_b1[tid];
  } else if (tid < 192) {
    const int o = tid - 64;
    sb[128 + o] = sd_b1[o]; sb[256 + o] = sd_b2[o]; sb[384 + o] = rc_b1[o];
  }

  {
    const float* sp = s_in + (size_t)b * 4096;
    const int j = tid >> 3, g = tid & 7;
    const float4 p0 = *(const float4*)(sp + j * 64 + g * 8);
    const float4 p1 = *(const float4*)(sp + j * 64 + g * 8 + 4);
    uint2 H0, L0, H1, L1;
    split4(p0, H0, L0);
    split4(p1, H1, L1);
    const int d = j * 64 + ((g ^ (j & 7)) * 8);
    *(uint4*)&sB0h[d] = make_uint4(H0.x, H0.y, H1.x, H1.y);
    *(uint4*)&sB0l[d] = make_uint4(L0.x, L0.y, L1.x, L1.y);
  }

  prep_w<64, 64, TPB_E>(sW + 0, sW + 4096, se_w1, tid);
  prep_w<64, 64, TPB_E>(sW + 8192, sW + 12288, se_w2, tid);
  prep_w<64, 128, TPB_E>(sW + 16384, sW + 24576, sd_w1, tid);
  __syncthreads();

  f32x4 a1[1][4];

  if (act4) {
    initb<1>(a1, sb + 0, o0, quad);
    run3<1, 2, 8, 4>(a1, sW + 0, sW + 4096, sB0h, sB0l, w, quad, l15);
    store_hl<1, 8>(a1, sB1h, sB1l, o0, quad, l15);
  }
  __syncthreads();

  if (act4) {
    initb<1>(a1, sb + 64, o0, quad);
    run3<1, 2, 8, 4>(a1, sW + 8192, sW + 12288, sB1h, sB1l, w, quad, l15);
    store_hl<1, 8>(a1, sB0h, sB0l, o0, quad, l15);
  }
  __syncthreads();

  {
    const int j = tid >> 3, g = tid & 7;
    const uint4 v = *(const uint4*)&sB0h[j * 64 + ((g ^ (j & 7)) * 8)];
    *(uint4*)&hB[(size_t)(b * 64 + j) * 64 + g * 8] = v;
  }

  initb<1>(a1, sb + 128, o0, quad);
  run3<1, 2, 8, 8>(a1, sW + 16384, sW + 24576, sB0h, sB0l, w, quad, l15);
  store_hl<1, 16>(a1, sB2h, sB2l, o0, quad, l15);
  __syncthreads();

  prep_w<128, 128, TPB_E>(sW + 0, sW + 16384, sd_w2, tid);
  __syncthreads();

  zeroa<1>(a1);
  run3<1, 4, 16, 8>(a1, sW + 0, sW + 16384, sB2h, sB2l, w, quad, l15);
  {
    float ps[4];
#pragma unroll
    for (int r = 0; r < 4; ++r) {
      float v = a1[0][0][r] + a1[0][1][r] + a1[0][2][r] + a1[0][3][r];
      v += __shfl_xor(v, 1, 64);
      v += __shfl_xor(v, 2, 64);
      v += __shfl_xor(v, 4, 64);
      v += __shfl_xor(v, 8, 64);
      ps[r] = v;
    }
    if (l15 == 0) {
#pragma unroll
      for (int r = 0; r < 4; ++r) sRed[o0 + quad * 4 + r] = ps[r];
    }
  }
  __syncthreads();
  if (tid < 128)
    atomicAdd(&out[b * 128 + tid], sRed[tid] * (1.0f / 64.0f) + sb[256 + tid]);

  if (do_bases) prep_w<64, 128, TPB_E>(sW + 0, sW + 8192, rc_w1, tid);
  if (do_pre)   prep_w<64, 128, TPB_E>(sW + 16384, sW + 24576, rc_w1 + 64 * 128, tid);
  __syncthreads();

  if (do_bases) {
    initb<1>(a1, sb + 384, o0, quad);
    run3<1, 2, 8, 8>(a1, sW + 0, sW + 8192, sB0h, sB0l, w, quad, l15);
#pragma unroll
    for (int s = 0; s < 4; ++s) {
      float4 v = make_float4(a1[0][s][0], a1[0][s][1], a1[0][s][2], a1[0][s][3]);
      *(float4*)&baseRcG[(size_t)(b * 64 + 16 * s + l15) * 128 + o0 + quad * 4] = v;
    }
  }
  if (do_pre) {
    zeroa<1>(a1);
    run3<1, 2, 8, 8>(a1, sW + 16384, sW + 24576, sB0h, sB0l, w, quad, l15);
#pragma unroll
    for (int s = 0; s < 4; ++s) {
      float4 v = make_float4(a1[0][s][0], a1[0][s][1], a1[0][s][2], a1[0][s][3]);
      *(float4*)&rc1pG[(size_t)((b * 8 + w) * 4 + s) * 256 + lane * 4] = v;
    }
  }
  __syncthreads();

  if (do_bases) prep_w<64, 64, TPB_E>(sW + 0, sW + 4096, an_w1, tid);
  if (do_pre)   prep_w<64, 64, TPB_E>(sW + 8192, sW + 12288, an_w1 + 64 * 64, tid);
  __syncthreads();

  if (act4) {
    if (do_bases) {
      initb<1>(a1, sb + 512, o0, quad);
      run3<1, 2, 8, 4>(a1, sW + 0, sW + 4096, sB0h, sB0l, w, quad, l15);
#pragma unroll
      for (int s = 0; s < 4; ++s) {
        float4 v = make_float4(a1[0][s][0], a1[0][s][1], a1[0][s][2], a1[0][s][3]);
        *(float4*)&baseAnG[(size_t)(b * 64 + 16 * s + l15) * 64 + o0 + quad * 4] = v;
      }
    }
    if (do_pre) {
      zeroa<1>(a1);
      run3<1, 2, 8, 4>(a1, sW + 8192, sW + 12288, sB0h, sB0l, w, quad, l15);
#pragma unroll
      for (int s = 0; s < 4; ++s) {
        float4 v = make_float4(a1[0][s][0], a1[0][s][1], a1[0][s][2], a1[0][s][3]);
        *(float4*)&an1pG[(size_t)((b * 4 + w) * 4 + s) * 256 + lane * 4] = v;
      }
    }
  }
}

// ---------------------------------------------------------------------------
// Kernel A2: weight prep into blob. (Unchanged.)
// ---------------------------------------------------------------------------
__global__ __launch_bounds__(TPB, 4) void prep_kernel(
    const float* __restrict__ rc_w1, const float* __restrict__ rc_w2,
    const float* __restrict__ rc_w3, const float* __restrict__ an_w1,
    const float* __restrict__ an_w2, u16* __restrict__ blob) {
  int idx = (int)blockIdx.x * TPB + threadIdx.x;
  if (idx >= 53248) return;
  int r, base, OK, T; const float* W; int Wld, krow0, twoTerm;
  if (idx < 8192)       { r = idx;         base = RC1F; OK = 8192;  T = 8; W = rc_w1; Wld = 128; krow0 = 64; twoTerm = 1; }
  else if (idx < 12288) { r = idx - 8192;  base = AN1F; OK = 4096;  T = 4; W = an_w1; Wld = 64;  krow0 = 64; twoTerm = 1; }
  else if (idx < 20480) { r = idx - 12288; base = AN2F; OK = 8192;  T = 8; W = an_w2; Wld = 128; krow0 = 0;  twoTerm = 0; }
  else if (idx < 36864) { r = idx - 20480; base = RC2F; OK = 16384; T = 8; W = rc_w2; Wld = 128; krow0 = 0;  twoTerm = 0; }
  else                  { r = idx - 36864; base = RC3F; OK = 16384; T = 8; W = rc_w3; Wld = 128; krow0 = 0;  twoTerm = 0; }
  const int u = r & 7;
  const int lane = (r >> 3) & 63;
  const int ct = r >> 9;
  const int c = (T == 8) ? (ct >> 3) : (ct >> 2);
  const int tg = (T == 8) ? (ct & 7) : (ct & 3);
  const int o = tg * 16 + (lane & 15);
  const int k = c * 32 + (lane >> 4) * 8 + u;
  const float x = W[(krow0 + k) * Wld + o];
  if (twoTerm) {
    u16 hi, lo; split_f16(x, hi, lo);
    blob[base + r] = hi;
    blob[base + OK + r] = lo;
  } else {
    blob[base + r] = f2h_rne(x);
  }
}

// ---------------------------------------------------------------------------
// MFMA layer helper for the pair kernel (A from global blob; B from LDS).
// ---------------------------------------------------------------------------
template<int MT, int NCHUNK, int RSG, int TILES>
__device__ __forceinline__ void run_layer1(f32x4 (&acc)[MT][4],
    const u16* __restrict__ blobL,
    const u16* __restrict__ sB, int tg0, int quad, int l15) {
  const int lane = quad * 16 + l15;
#pragma unroll
  for (int c = 0; c < NCHUNK; ++c) {
    f16x8 Ah[MT];
#pragma unroll
    for (int t = 0; t < MT; ++t)
      Ah[t] = *(const f16x8*)(blobL + ((c * TILES + tg0 + t) * 64 + lane) * 8);
    const int slot = (4 * c + quad) ^ (l15 & 7);
    f16x8 Bh[4];
#pragma unroll
    for (int s = 0; s < 4; ++s)
      Bh[s] = *(const f16x8*)&sB[(16 * s + l15) * (RSG * 8) + slot * 8];
#pragma unroll
    for (int t = 0; t < MT; ++t)
#pragma unroll
      for (int s = 0; s < 4; ++s)
        acc[t][s] = __builtin_amdgcn_mfma_f32_16x16x32_f16(Ah[t], Bh[s], acc[t][s], 0, 0, 0);
  }
}

template<int MT, int RSG>
__device__ __forceinline__ void store_acts_pk(const f32x4 (&acc)[MT][4],
                                              u16* dst, int o0, int quad, int l15) {
#pragma unroll
  for (int t = 0; t < MT; ++t) {
    const int ob = o0 + 16 * t + quad * 4;
    const int slot = (ob >> 3) ^ (l15 & 7);
    const int e = ob & 7;
#pragma unroll
    for (int s = 0; s < 4; ++s) {
      const int j = 16 * s + l15;
      uint2 pk;
      pk.x = pack_f16(fmaxf(acc[t][s][0], 0.f), fmaxf(acc[t][s][1], 0.f));
      pk.y = pack_f16(fmaxf(acc[t][s][2], 0.f), fmaxf(acc[t][s][3], 0.f));
      *(uint2*)&dst[j * (RSG * 8) + slot * 8 + e] = pk;
    }
  }
}

// ---------------------------------------------------------------------------
// Kernel B (MFMA) R14: TWO i's per block. 512 threads; waves 0-3 -> i0,
// waves 4-7 -> i1. LDS ~54 KB -> 3 blocks/CU = 24 waves/CU resident (vs ~12
// at R13's 256-thr/28KB/LB4) — the kernel is latency-bound (MfmaUtil 23,
// VALUBusy 52, HBM 6%, nothing saturated), so double the waves. Shared
// weights/pre lines between halves (same CU -> L1 hits); atomics halve.
// Per-thread state unchanged -> VGPR should stay ~64 (cap 128 at LB(512,4);
// residency needs <=85 — check VGPR_Count).
// ---------------------------------------------------------------------------
__global__ __launch_bounds__(TPB_P, 4) void pair_mfma_kernel(
    const u16* __restrict__ hB, const u16* __restrict__ blob,
    const float* __restrict__ baseRcG, const float* __restrict__ baseAnG,
    const float* __restrict__ rc1pG, const float* __restrict__ an1pG,
    int has_bases, int has_pre,
    const float* __restrict__ rc_w1, const float* __restrict__ rc_b1,
    const float* __restrict__ rc_b2, const float* __restrict__ rc_b3,
    const float* __restrict__ an_w1, const float* __restrict__ an_b1,
    const float* __restrict__ an_b2,
    float* __restrict__ out) {
  __shared__ __align__(16) u16 sAct[2 * 64 * 128];  // 32 KB (16K per half)
  __shared__ __align__(16) u16 sAn[2 * 64 * 64];    // 16 KB
  // scratch per half: [0,64) dist | [64,128) hi (fallback); reused as red at end
  __shared__ float scratch[2 * 128];
  __shared__ float sBaseRc[2 * 128], sBaseAn[2 * 64];
  __shared__ float sW1d[128], sAnd[64], sB2[128], sB3[128], sAb2[128];

  const int tid = threadIdx.x;
  const int ht = tid & 255;          // role index within half
  const int ih = tid >> 8;           // which i of the pair
  const int w4 = (tid >> 6) & 3;     // wave role within half
  const int lane = tid & 63;
  const int quad = lane >> 4, l15 = lane & 15;
  const int b = blockIdx.x >> 5;
  const int i = ((blockIdx.x & 31) << 1) | ih;
  const int o0 = w4 * 32;
  const int o0a = w4 * 16;

  u16* sActP = sAct + ih * 8192;
  u16* sAnP  = sAn + ih * 4096;
  float* sDist = scratch + ih * 128;       // [0,64)
  float* sHi   = scratch + ih * 128 + 64;  // fallback only
  float* bRcP  = sBaseRc + ih * 128;
  float* bAnP  = sBaseAn + ih * 64;

  f32x4 accR[2][4];
  f32x4 accN[1][4];

  if (has_pre) {
    // ======== fast path ========
    // shared weights: both halves write identical values (benign duplicate)
    if (ht < 128) {
      sW1d[ht] = rc_w1[128 * 128 + ht];
      sB2[ht] = rc_b2[ht]; sB3[ht] = rc_b3[ht]; sAb2[ht] = an_b2[ht];
    } else if (ht < 192) {
      sAnd[ht - 128] = an_w1[128 * 64 + (ht - 128)];
    } else {
      const int j = ht - 192;
      const float hi0 = h2f(hB[(b * 64 + i) * 64 + 0]);
      const float hi1 = h2f(hB[(b * 64 + i) * 64 + 1]);
      const ushort2 hj = *(const ushort2*)&hB[(b * 64 + j) * 64];
      const float d0 = hi0 - h2f(hj.x), d1 = hi1 - h2f(hj.y);
      sDist[j] = d0 * d0 + d1 * d1;
    }
    if (ht < 32)
      ((float4*)bRcP)[ht] = ((const float4*)(baseRcG + (size_t)(b * 64 + i) * 128))[ht];
    else if (ht < 48)
      ((float4*)bAnP)[ht - 32] = ((const float4*)(baseAnG + (size_t)(b * 64 + i) * 64))[ht - 32];
    __syncthreads();

    float bbR[2][4], wwR[2][4], bbN[4], wwN[4];
#pragma unroll
    for (int t = 0; t < 2; ++t) {
      ld4(bbR[t], &bRcP[o0 + 16 * t + quad * 4]);
      ld4(wwR[t], &sW1d[o0 + 16 * t + quad * 4]);
    }
    ld4(bbN, &bAnP[o0a + quad * 4]);
    ld4(wwN, &sAnd[o0a + quad * 4]);
    // pre data is i-independent: both halves read the same lines (L1 hits)
    const float* pR = rc1pG + (size_t)(b * 8 + 2 * w4) * 1024 + lane * 4;
    const float* pA = an1pG + (size_t)(b * 4 + w4) * 1024 + lane * 4;
#pragma unroll
    for (int s = 0; s < 4; ++s) {
      const float dj = sDist[16 * s + l15];
#pragma unroll
      for (int t = 0; t < 2; ++t) {
        const float4 pre = *(const float4*)(pR + t * 1024 + s * 256);
        f32x4 a;
        a[0] = pre.x + fmaf(dj, wwR[t][0], bbR[t][0]);
        a[1] = pre.y + fmaf(dj, wwR[t][1], bbR[t][1]);
        a[2] = pre.z + fmaf(dj, wwR[t][2], bbR[t][2]);
        a[3] = pre.w + fmaf(dj, wwR[t][3], bbR[t][3]);
        accR[t][s] = a;
      }
      const float4 pre = *(const float4*)(pA + s * 256);
      f32x4 a;
      a[0] = pre.x + fmaf(dj, wwN[0], bbN[0]);
      a[1] = pre.y + fmaf(dj, wwN[1], bbN[1]);
      a[2] = pre.z + fmaf(dj, wwN[2], bbN[2]);
      a[3] = pre.w + fmaf(dj, wwN[3], bbN[3]);
      accN[0][s] = a;
    }
    store_acts_pk<1, 8>(accN, sAnP, o0a, quad, l15);
    store_acts_pk<2, 16>(accR, sActP, o0, quad, l15);
    __syncthreads();
  } else {
    // ======== fallback: L1 via MFMA (each half independent) ========
    {
      const float4* srcJ = (const float4*)(hB + b * 4096);
      for (int idx = ht; idx < 512; idx += 256) {
        const int row = idx >> 3, g = idx & 7;
        *(float4*)&sActP[row * 128 + ((g ^ (row & 7)) * 8)] = srcJ[idx];
      }
    }
    if (has_bases) {
      const float4* bR = (const float4*)(baseRcG + (size_t)(b * 64 + i) * 128);
      const float4* bA = (const float4*)(baseAnG + (size_t)(b * 64 + i) * 64);
      if (ht < 32) ((float4*)bRcP)[ht] = bR[ht];
      else if (ht < 48) ((float4*)bAnP)[ht - 32] = bA[ht - 32];
    }
    if (ht < 64) sHi[ht] = h2f(hB[(b * 64 + i) * 64 + ht]);
    if (ht < 128) {
      sW1d[ht] = rc_w1[128 * 128 + ht];
      sB2[ht] = rc_b2[ht]; sB3[ht] = rc_b3[ht]; sAb2[ht] = an_b2[ht];
    } else if (ht < 192) {
      sAnd[ht - 128] = an_w1[128 * 64 + (ht - 128)];
    }
    __syncthreads();
    if (!has_bases) {
      if (ht < 128) {
        float acc = rc_b1[ht];
        for (int k = 0; k < 64; ++k) acc = fmaf(sHi[k], rc_w1[k * 128 + ht], acc);
        bRcP[ht] = acc;
      } else if (ht < 192) {
        const int o = ht - 128;
        float acc = an_b1[o];
        for (int k = 0; k < 64; ++k) acc = fmaf(sHi[k], an_w1[k * 64 + o], acc);
        bAnP[o] = acc;
      }
    }
    if (ht >= 192) {
      const int j = ht - 192;
      const int base = j * 128 + ((0 ^ (j & 7)) * 8);
      const float d0 = sHi[0] - h2f(sActP[base + 0]);
      const float d1 = sHi[1] - h2f(sActP[base + 1]);
      sDist[j] = d0 * d0 + d1 * d1;
    }
    __syncthreads();

    {
      float bbR[2][4], wwR[2][4], bbN[4], wwN[4];
#pragma unroll
      for (int t = 0; t < 2; ++t) {
        ld4(bbR[t], &bRcP[o0 + 16 * t + quad * 4]);
        ld4(wwR[t], &sW1d[o0 + 16 * t + quad * 4]);
      }
      ld4(bbN, &bAnP[o0a + quad * 4]);
      ld4(wwN, &sAnd[o0a + quad * 4]);
#pragma unroll
      for (int s = 0; s < 4; ++s) {
        const float dj = sDist[16 * s + l15];
#pragma unroll
        for (int t = 0; t < 2; ++t) {
          f32x4 a;
#pragma unroll
          for (int r = 0; r < 4; ++r) a[r] = fmaf(dj, wwR[t][r], bbR[t][r]);
          accR[t][s] = a;
        }
        f32x4 a;
#pragma unroll
        for (int r = 0; r < 4; ++r) a[r] = fmaf(dj, wwN[r], bbN[r]);
        accN[0][s] = a;
      }
    }
    {
      const int lane64 = quad * 16 + l15;
#pragma unroll
      for (int c = 0; c < 2; ++c) {
        f16x8 Ah[2], Al[2], AhN, AlN;
#pragma unroll
        for (int t = 0; t < 2; ++t) {
          const u16* p = blob + RC1F + ((c * 8 + 2 * w4 + t) * 64 + lane64) * 8;
          Ah[t] = *(const f16x8*)p;
          Al[t] = *(const f16x8*)(p + 8192);
        }
        {
          const u16* p = blob + AN1F + ((c * 4 + w4) * 64 + lane64) * 8;
          AhN = *(const f16x8*)p;
          AlN = *(const f16x8*)(p + 4096);
        }
        const int slot = (4 * c + quad) ^ (l15 & 7);
        f16x8 Bh[4];
#pragma unroll
        for (int s = 0; s < 4; ++s)
          Bh[s] = *(const f16x8*)&sActP[(16 * s + l15) * 128 + slot * 8];
#pragma unroll
        for (int s = 0; s < 4; ++s) {
#pragma unroll
          for (int t = 0; t < 2; ++t) {
            f32x4 a = accR[t][s];
            a = __builtin_amdgcn_mfma_f32_16x16x32_f16(Ah[t], Bh[s], a, 0, 0, 0);
            a = __builtin_amdgcn_mfma_f32_16x16x32_f16(Al[t], Bh[s], a, 0, 0, 0);
            accR[t][s] = a;
          }
          f32x4 a = accN[0][s];
          a = __builtin_amdgcn_mfma_f32_16x16x32_f16(AhN, Bh[s], a, 0, 0, 0);
          a = __builtin_amdgcn_mfma_f32_16x16x32_f16(AlN, Bh[s], a, 0, 0, 0);
          accN[0][s] = a;
        }
      }
    }
    store_acts_pk<1, 8>(accN, sAnP, o0a, quad, l15);
    __syncthreads();
    store_acts_pk<2, 16>(accR, sActP, o0, quad, l15);
    __syncthreads();
  }

  // ======== common tail: rc2 + an2 together, sigmoid, store, rc3 ========
  {
    float bb[2][4];
#pragma unroll
    for (int t = 0; t < 2; ++t) ld4(bb[t], &sB2[o0 + 16 * t + quad * 4]);
#pragma unroll
    for (int t = 0; t < 2; ++t)
#pragma unroll
      for (int s = 0; s < 4; ++s) {
        f32x4 a;
#pragma unroll
        for (int r = 0; r < 4; ++r) a[r] = bb[t][r];
        accR[t][s] = a;
      }
  }
  f32x4 accT[2][4];
  {
    float bb[2][4];
#pragma unroll
    for (int t = 0; t < 2; ++t) ld4(bb[t], &sAb2[o0 + 16 * t + quad * 4]);
#pragma unroll
    for (int t = 0; t < 2; ++t)
#pragma unroll
      for (int s = 0; s < 4; ++s) {
        f32x4 a;
#pragma unroll
        for (int r = 0; r < 4; ++r) a[r] = bb[t][r];
        accT[t][s] = a;
      }
  }
  __builtin_amdgcn_s_setprio(1);
  run_layer1<2, 4, 16, 8>(accR, blob + RC2F, sActP, 2 * w4, quad, l15);
  run_layer1<2, 2, 8, 8>(accT, blob + AN2F, sAnP, 2 * w4, quad, l15);
  __builtin_amdgcn_s_setprio(0);
  float att[2][4][4];
#pragma unroll
  for (int t = 0; t < 2; ++t)
#pragma unroll
    for (int s = 0; s < 4; ++s)
#pragma unroll
      for (int r = 0; r < 4; ++r)
        att[t][s][r] = __builtin_amdgcn_rcpf(1.0f + __expf(-accT[t][s][r]));
  __syncthreads();
  store_acts_pk<2, 16>(accR, sActP, o0, quad, l15);
  __syncthreads();

  // ---- rc-L3 (init = rc_b3) + rel*att + reduce over j
  {
    float bb[2][4];
#pragma unroll
    for (int t = 0; t < 2; ++t) ld4(bb[t], &sB3[o0 + 16 * t + quad * 4]);
#pragma unroll
    for (int t = 0; t < 2; ++t)
#pragma unroll
      for (int s = 0; s < 4; ++s) {
        f32x4 a;
#pragma unroll
        for (int r = 0; r < 4; ++r) a[r] = bb[t][r];
        accR[t][s] = a;
      }
  }
  __builtin_amdgcn_s_setprio(1);
  run_layer1<2, 4, 16, 8>(accR, blob + RC3F, sActP, 2 * w4, quad, l15);
  __builtin_amdgcn_s_setprio(0);
  float ps[2][4] = {{0.f, 0.f, 0.f, 0.f}, {0.f, 0.f, 0.f, 0.f}};
#pragma unroll
  for (int t = 0; t < 2; ++t)
#pragma unroll
    for (int s = 0; s < 4; ++s)
#pragma unroll
      for (int r = 0; r < 4; ++r) {
        const float rel = fmaxf(accR[t][s][r], 0.f);
        ps[t][r] = fmaf(rel, att[t][s][r], ps[t][r]);
      }
#pragma unroll
  for (int t = 0; t < 2; ++t)
#pragma unroll
    for (int r = 0; r < 4; ++r) {
      float v = ps[t][r];
      v += __shfl_xor(v, 1, 64);
      v += __shfl_xor(v, 2, 64);
      v += __shfl_xor(v, 4, 64);
      v += __shfl_xor(v, 8, 64);
      ps[t][r] = v;
    }
  // scratch reused as per-half reduction buffer (dist/hi dead by now)
  if (l15 == 0) {
#pragma unroll
    for (int t = 0; t < 2; ++t)
#pragma unroll
      for (int r = 0; r < 4; ++r)
        scratch[ih * 128 + o0 + 16 * t + quad * 4 + r] = ps[t][r];
  }
  __syncthreads();
  if (tid < 128)
    atomicAdd(&out[b * 128 + tid],
              (scratch[tid] + scratch[128 + tid]) * (1.0f / 4096.0f));
}

extern "C" void kernel_launch(void* const* d_in, const int* in_sizes, int n_in,
                              void* d_out, int out_size, void* d_ws, size_t ws_size,
                              hipStream_t stream) {
  const float* s     = (const float*)d_in[0];
  const float* se_w1 = (const float*)d_in[1];
  const float* se_b1 = (const float*)d_in[2];
  const float* se_w2 = (const float*)d_in[3];
  const float* se_b2 = (const float*)d_in[4];
  const float* sd_w1 = (const float*)d_in[5];
  const float* sd_b1 = (const float*)d_in[6];
  const float* sd_w2 = (const float*)d_in[7];
  const float* sd_b2 = (const float*)d_in[8];
  const float* rc_w1 = (const float*)d_in[9];
  const float* rc_b1 = (const float*)d_in[10];
  const float* rc_w2 = (const float*)d_in[11];
  const float* rc_b2 = (const float*)d_in[12];
  const float* rc_w3 = (const float*)d_in[13];
  const float* rc_b3 = (const float*)d_in[14];
  const float* an_w1 = (const float*)d_in[15];
  const float* an_b1 = (const float*)d_in[16];
  const float* an_w2 = (const float*)d_in[17];
  const float* an_b2 = (const float*)d_in[18];
  float* out = (float*)d_out;
  u16* hB   = (u16*)d_ws;
  u16* blob = hB + BLOB_U16;
  float* baseRcG = (float*)d_ws + BASE_RC_F32;
  float* baseAnG = (float*)d_ws + BASE_AN_F32;
  float* rc1pG   = (float*)d_ws + RC1P_F32;
  float* an1pG   = (float*)d_ws + AN1P_F32;
  const int has_pre   = (ws_size >= WS_NEED_PRE) ? 1 : 0;
  const int has_bases = (ws_size >= WS_NEED_BASES) ? 1 : 0;
  (void)n_in; (void)in_sizes;

  hipMemsetAsync(d_out, 0, (size_t)out_size * sizeof(float), stream);
  enc_kernel<<<ENC_BLOCKS, TPB_E, 0, stream>>>(s, se_w1, se_b1, se_w2, se_b2,
                                               sd_w1, sd_b1, sd_w2, sd_b2,
                                               rc_w1, rc_b1, an_w1, an_b1,
                                               hB, baseRcG, baseAnG, rc1pG, an1pG,
                                               has_bases, has_pre, out);
  prep_kernel<<<PREP_BLOCKS, TPB, 0, stream>>>(rc_w1, rc_w2, rc_w3, an_w1, an_w2, blob);
  pair_mfma_kernel<<<4096, TPB_P, 0, stream>>>(hB, blob, baseRcG, baseAnG, rc1pG, an1pG,
                                               has_bases, has_pre,
                                               rc_w1, rc_b1, rc_b2, rc_b3,
                                               an_w1, an_b1, an_b2, out);
}

// Round 6
// 174.589 us; speedup vs baseline: 1.0586x; 1.0586x over previous
//
#include <hip/hip_runtime.h>
#include <math.h>

#define TPB 256
#define TPB_E 512

typedef unsigned short u16;
typedef unsigned int u32;
typedef __attribute__((ext_vector_type(8))) _Float16 f16x8;
typedef __attribute__((ext_vector_type(4))) float f32x4;

// ---------------- ws layout ----------------
#define BLOB_U16 524288
#define BASE_RC_F32 327680
#define BASE_AN_F32 1376256
#define RC1P_F32 1900544
#define AN1P_F32 2949120
#define WS_NEED_BASES ((size_t)1900544 * 4)  // ~7.6 MB
#define WS_NEED_PRE   ((size_t)3473408 * 4)  // ~13.9 MB
// blob-internal u16 offsets (hi[OK] then lo[OK]; lo unused for hi-only layers)
#define RC1F 0       // O=128, K=64  T=8 OK=8192  [2-term, fallback only]
#define AN1F 16384   // O=64,  K=64  T=4 OK=4096  [2-term, fallback only]
#define AN2F 24576   // O=128, K=64  T=8 OK=8192  [hi-only RNE, scaled -log2e]
#define RC2F 40960   // O=128, K=128 T=8 OK=16384 [hi-only RNE]
#define RC3F 73728   // O=128, K=128 T=8 OK=16384 [hi-only RNE]

// R15: enc+prep re-fused (prep ~2us; fewer dispatches — residual is fixed
// harness overhead ~97us, so trim enqueued ops). Blocks 0..127 encoder,
// 128..231 prep (104 x 512 = 53248 threads).
#define ENC_BLOCKS 128
#define FUSED_BLOCKS (ENC_BLOCKS + 104)

// -log2(e): AN2F weights and an_b2 are pre-scaled by this so
// sigmoid(z) = rcp(1 + exp2(accT)) with accT = -z*log2e (v_exp_f32 is 2^x).
#define NEG_LOG2E -1.4426950408889634f

__device__ __forceinline__ float h2f(u16 b) {
  return (float)__builtin_bit_cast(_Float16, b);
}
__device__ __forceinline__ u16 f2h_rne(float x) {
  return __builtin_bit_cast(u16, (_Float16)x);  // RNE
}
__device__ __forceinline__ void split_f16(float x, u16& hi, u16& lo) {
  _Float16 h = (_Float16)x;
  hi = __builtin_bit_cast(u16, h);
  lo = __builtin_bit_cast(u16, (_Float16)(x - (float)h));
}
__device__ __forceinline__ unsigned pack_f16(float v0, float v1) {
  auto h = __builtin_amdgcn_cvt_pkrtz(v0, v1);
  return __builtin_bit_cast(unsigned, h);
}
__device__ __forceinline__ void split4(const float4 v, uint2& H, uint2& L) {
  _Float16 h0 = (_Float16)v.x, h1 = (_Float16)v.y;
  _Float16 h2 = (_Float16)v.z, h3 = (_Float16)v.w;
  _Float16 l0 = (_Float16)(v.x - (float)h0), l1 = (_Float16)(v.y - (float)h1);
  _Float16 l2 = (_Float16)(v.z - (float)h2), l3 = (_Float16)(v.w - (float)h3);
  H.x = (u32)__builtin_bit_cast(u16, h0) | ((u32)__builtin_bit_cast(u16, h1) << 16);
  H.y = (u32)__builtin_bit_cast(u16, h2) | ((u32)__builtin_bit_cast(u16, h3) << 16);
  L.x = (u32)__builtin_bit_cast(u16, l0) | ((u32)__builtin_bit_cast(u16, l1) << 16);
  L.y = (u32)__builtin_bit_cast(u16, l2) | ((u32)__builtin_bit_cast(u16, l3) << 16);
}
__device__ __forceinline__ void ld4(float r[4], const float* p) {
  float4 v = *(const float4*)p;
  r[0] = v.x; r[1] = v.y; r[2] = v.z; r[3] = v.w;
}

// ---------------------------------------------------------------------------
// Weight prep into LDS A-fragments (hi/lo), enc role. For elem (o,k):
// idx = ((k>>5)*(O/16) + (o>>4))*512 + ((k>>3)&3)*128 + (o&15)*8 + (k&7)
// ---------------------------------------------------------------------------
template<int KDIM, int ODIM, int NT>
__device__ __forceinline__ void prep_w(u16* __restrict__ hi, u16* __restrict__ lo,
                                       const float* __restrict__ W, int tid) {
  constexpr int N = KDIM * ODIM / NT;
  constexpr int BATCH = (N < 16) ? N : 16;
  constexpr int OSH = (ODIM == 128) ? 7 : 6;
#pragma unroll
  for (int base = 0; base < N; base += BATCH) {
    float v[BATCH];
#pragma unroll
    for (int i = 0; i < BATCH; ++i) v[i] = W[(base + i) * NT + tid];
#pragma unroll
    for (int i = 0; i < BATCH; ++i) {
      const int e = (base + i) * NT + tid;
      const int k = e >> OSH, o = e & (ODIM - 1);
      const int idx = ((k >> 5) * (ODIM >> 4) + (o >> 4)) * 512 +
                      ((k >> 3) & 3) * 128 + (o & 15) * 8 + (k & 7);
      const float x = v[i];
      const _Float16 h = (_Float16)x;
      hi[idx] = __builtin_bit_cast(u16, h);
      lo[idx] = __builtin_bit_cast(u16, (_Float16)(x - (float)h));
    }
  }
}

// 3-term split MFMA: acc += (Whi+Wlo)@(Xhi+Xlo) dropping Wlo*Xlo (~2^-22 err)
template<int MT, int NCHUNK, int RSG, int TILES>
__device__ __forceinline__ void run3(f32x4 (&acc)[MT][4],
    const u16* __restrict__ wHi, const u16* __restrict__ wLo,
    const u16* __restrict__ bHi, const u16* __restrict__ bLo,
    int tg0, int quad, int l15) {
  const int lane = quad * 16 + l15;
#pragma unroll
  for (int c = 0; c < NCHUNK; ++c) {
    f16x8 Ah[MT], Al[MT];
#pragma unroll
    for (int t = 0; t < MT; ++t) {
      const int off = ((c * TILES + tg0 + t) * 64 + lane) * 8;
      Ah[t] = *(const f16x8*)(wHi + off);
      Al[t] = *(const f16x8*)(wLo + off);
    }
    const int slot = (4 * c + quad) ^ (l15 & 7);
    f16x8 Bh[4], Bl[4];
#pragma unroll
    for (int s = 0; s < 4; ++s) {
      const int off = (16 * s + l15) * (RSG * 8) + slot * 8;
      Bh[s] = *(const f16x8*)(bHi + off);
      Bl[s] = *(const f16x8*)(bLo + off);
    }
#pragma unroll
    for (int t = 0; t < MT; ++t)
#pragma unroll
      for (int s = 0; s < 4; ++s) {
        f32x4 a = acc[t][s];
        a = __builtin_amdgcn_mfma_f32_16x16x32_f16(Ah[t], Bh[s], a, 0, 0, 0);
        a = __builtin_amdgcn_mfma_f32_16x16x32_f16(Al[t], Bh[s], a, 0, 0, 0);
        a = __builtin_amdgcn_mfma_f32_16x16x32_f16(Ah[t], Bl[s], a, 0, 0, 0);
        acc[t][s] = a;
      }
  }
}

template<int MT, int RSG>
__device__ __forceinline__ void store_hl(const f32x4 (&acc)[MT][4],
    u16* __restrict__ dH, u16* __restrict__ dL, int o0, int quad, int l15) {
#pragma unroll
  for (int t = 0; t < MT; ++t) {
    const int ob = o0 + 16 * t + quad * 4;
    const int slot = (ob >> 3) ^ (l15 & 7);
    const int e = ob & 7;
#pragma unroll
    for (int s = 0; s < 4; ++s) {
      const int j = 16 * s + l15;
      float4 v = make_float4(fmaxf(acc[t][s][0], 0.f), fmaxf(acc[t][s][1], 0.f),
                             fmaxf(acc[t][s][2], 0.f), fmaxf(acc[t][s][3], 0.f));
      uint2 H, L;
      split4(v, H, L);
      *(uint2*)&dH[j * (RSG * 8) + slot * 8 + e] = H;
      *(uint2*)&dL[j * (RSG * 8) + slot * 8 + e] = L;
    }
  }
}

template<int MT>
__device__ __forceinline__ void initb(f32x4 (&acc)[MT][4], const float* bias,
                                      int o0, int quad) {
#pragma unroll
  for (int t = 0; t < MT; ++t) {
    float bb[4];
    ld4(bb, &bias[o0 + 16 * t + quad * 4]);
#pragma unroll
    for (int s = 0; s < 4; ++s) {
      f32x4 a;
#pragma unroll
      for (int r = 0; r < 4; ++r) a[r] = bb[r];
      acc[t][s] = a;
    }
  }
}
template<int MT>
__device__ __forceinline__ void zeroa(f32x4 (&acc)[MT][4]) {
#pragma unroll
  for (int t = 0; t < MT; ++t)
#pragma unroll
    for (int s = 0; s < 4; ++s) {
      f32x4 a;
#pragma unroll
      for (int r = 0; r < 4; ++r) a[r] = 0.f;
      acc[t][s] = a;
    }
}

// ---------------------------------------------------------------------------
// Kernel A (fused): blocks 0..127 = MFMA encoder (one b each); blocks
// 128..231 = weight prep into blob. Encoder writes out[b] DIRECTLY (covers
// all 128 outputs once) so no hipMemset is needed; pair atomicAdds on top
// (stream order guarantees enc completes first).
// ---------------------------------------------------------------------------
__global__ __launch_bounds__(TPB_E, 1) void enc_prep_kernel(
    const float* __restrict__ s_in,
    const float* __restrict__ se_w1, const float* __restrict__ se_b1,
    const float* __restrict__ se_w2, const float* __restrict__ se_b2,
    const float* __restrict__ sd_w1, const float* __restrict__ sd_b1,
    const float* __restrict__ sd_w2, const float* __restrict__ sd_b2,
    const float* __restrict__ rc_w1, const float* __restrict__ rc_b1,
    const float* __restrict__ rc_w2, const float* __restrict__ rc_w3,
    const float* __restrict__ an_w1, const float* __restrict__ an_b1,
    const float* __restrict__ an_w2,
    u16* __restrict__ hB, u16* __restrict__ blob,
    float* __restrict__ baseRcG, float* __restrict__ baseAnG,
    float* __restrict__ rc1pG, float* __restrict__ an1pG,
    int do_bases, int do_pre,
    float* __restrict__ out) {
  if (blockIdx.x >= ENC_BLOCKS) {
    // ---- prep role: fragment-linear blob for the pair kernel
    int idx = (int)(blockIdx.x - ENC_BLOCKS) * TPB_E + threadIdx.x;
    if (idx >= 53248) return;
    int r, base, OK, T; const float* W; int Wld, krow0, twoTerm, isAn2;
    if (idx < 8192)       { r = idx;         base = RC1F; OK = 8192;  T = 8; W = rc_w1; Wld = 128; krow0 = 64; twoTerm = 1; isAn2 = 0; }
    else if (idx < 12288) { r = idx - 8192;  base = AN1F; OK = 4096;  T = 4; W = an_w1; Wld = 64;  krow0 = 64; twoTerm = 1; isAn2 = 0; }
    else if (idx < 20480) { r = idx - 12288; base = AN2F; OK = 8192;  T = 8; W = an_w2; Wld = 128; krow0 = 0;  twoTerm = 0; isAn2 = 1; }
    else if (idx < 36864) { r = idx - 20480; base = RC2F; OK = 16384; T = 8; W = rc_w2; Wld = 128; krow0 = 0;  twoTerm = 0; isAn2 = 0; }
    else                  { r = idx - 36864; base = RC3F; OK = 16384; T = 8; W = rc_w3; Wld = 128; krow0 = 0;  twoTerm = 0; isAn2 = 0; }
    const int u = r & 7;
    const int lane = (r >> 3) & 63;
    const int ct = r >> 9;
    const int c = (T == 8) ? (ct >> 3) : (ct >> 2);
    const int tg = (T == 8) ? (ct & 7) : (ct & 3);
    const int o = tg * 16 + (lane & 15);
    const int k = c * 32 + (lane >> 4) * 8 + u;
    float x = W[(krow0 + k) * Wld + o];
    if (isAn2) x *= NEG_LOG2E;  // fold sigmoid's -log2(e) into an2 weights
    if (twoTerm) {
      u16 hi, lo; split_f16(x, hi, lo);
      blob[base + r] = hi;
      blob[base + OK + r] = lo;
    } else {
      blob[base + r] = f2h_rne(x);
    }
    return;
  }

  // ================= MFMA encoder: one block per b =================
  __shared__ __align__(16) u16 sW[32768];
  __shared__ __align__(16) u16 sB0h[4096], sB0l[4096];
  __shared__ __align__(16) u16 sB1h[4096], sB1l[4096];
  __shared__ __align__(16) u16 sB2h[8192], sB2l[8192];
  __shared__ float sb[576];
  __shared__ float sRed[128];

  const int tid = threadIdx.x;
  const int w = tid >> 6, lane = tid & 63;
  const int quad = lane >> 4, l15 = lane & 15;
  const int b = blockIdx.x;
  const int o0 = w * 16;
  const bool act4 = (w < 4);

  if (tid < 64) {
    sb[tid] = se_b1[tid]; sb[64 + tid] = se_b2[tid]; sb[512 + tid] = an_b1[tid];
  } else if (tid < 192) {
    const int o = tid - 64;
    sb[128 + o] = sd_b1[o]; sb[256 + o] = sd_b2[o]; sb[384 + o] = rc_b1[o];
  }

  {
    const float* sp = s_in + (size_t)b * 4096;
    const int j = tid >> 3, g = tid & 7;
    const float4 p0 = *(const float4*)(sp + j * 64 + g * 8);
    const float4 p1 = *(const float4*)(sp + j * 64 + g * 8 + 4);
    uint2 H0, L0, H1, L1;
    split4(p0, H0, L0);
    split4(p1, H1, L1);
    const int d = j * 64 + ((g ^ (j & 7)) * 8);
    *(uint4*)&sB0h[d] = make_uint4(H0.x, H0.y, H1.x, H1.y);
    *(uint4*)&sB0l[d] = make_uint4(L0.x, L0.y, L1.x, L1.y);
  }

  prep_w<64, 64, TPB_E>(sW + 0, sW + 4096, se_w1, tid);
  prep_w<64, 64, TPB_E>(sW + 8192, sW + 12288, se_w2, tid);
  prep_w<64, 128, TPB_E>(sW + 16384, sW + 24576, sd_w1, tid);
  __syncthreads();

  f32x4 a1[1][4];

  if (act4) {
    initb<1>(a1, sb + 0, o0, quad);
    run3<1, 2, 8, 4>(a1, sW + 0, sW + 4096, sB0h, sB0l, w, quad, l15);
    store_hl<1, 8>(a1, sB1h, sB1l, o0, quad, l15);
  }
  __syncthreads();

  if (act4) {
    initb<1>(a1, sb + 64, o0, quad);
    run3<1, 2, 8, 4>(a1, sW + 8192, sW + 12288, sB1h, sB1l, w, quad, l15);
    store_hl<1, 8>(a1, sB0h, sB0l, o0, quad, l15);
  }
  __syncthreads();

  {
    const int j = tid >> 3, g = tid & 7;
    const uint4 v = *(const uint4*)&sB0h[j * 64 + ((g ^ (j & 7)) * 8)];
    *(uint4*)&hB[(size_t)(b * 64 + j) * 64 + g * 8] = v;
  }

  initb<1>(a1, sb + 128, o0, quad);
  run3<1, 2, 8, 8>(a1, sW + 16384, sW + 24576, sB0h, sB0l, w, quad, l15);
  store_hl<1, 16>(a1, sB2h, sB2l, o0, quad, l15);
  __syncthreads();

  prep_w<128, 128, TPB_E>(sW + 0, sW + 16384, sd_w2, tid);
  __syncthreads();

  zeroa<1>(a1);
  run3<1, 4, 16, 8>(a1, sW + 0, sW + 16384, sB2h, sB2l, w, quad, l15);
  {
    float ps[4];
#pragma unroll
    for (int r = 0; r < 4; ++r) {
      float v = a1[0][0][r] + a1[0][1][r] + a1[0][2][r] + a1[0][3][r];
      v += __shfl_xor(v, 1, 64);
      v += __shfl_xor(v, 2, 64);
      v += __shfl_xor(v, 4, 64);
      v += __shfl_xor(v, 8, 64);
      ps[r] = v;
    }
    if (l15 == 0) {
#pragma unroll
      for (int r = 0; r < 4; ++r) sRed[o0 + quad * 4 + r] = ps[r];
    }
  }
  __syncthreads();
  // direct write (full coverage) — replaces memset + atomicAdd
  if (tid < 128)
    out[b * 128 + tid] = sRed[tid] * (1.0f / 64.0f) + sb[256 + tid];

  if (do_bases) prep_w<64, 128, TPB_E>(sW + 0, sW + 8192, rc_w1, tid);
  if (do_pre)   prep_w<64, 128, TPB_E>(sW + 16384, sW + 24576, rc_w1 + 64 * 128, tid);
  __syncthreads();

  if (do_bases) {
    initb<1>(a1, sb + 384, o0, quad);
    run3<1, 2, 8, 8>(a1, sW + 0, sW + 8192, sB0h, sB0l, w, quad, l15);
#pragma unroll
    for (int s = 0; s < 4; ++s) {
      float4 v = make_float4(a1[0][s][0], a1[0][s][1], a1[0][s][2], a1[0][s][3]);
      *(float4*)&baseRcG[(size_t)(b * 64 + 16 * s + l15) * 128 + o0 + quad * 4] = v;
    }
  }
  if (do_pre) {
    zeroa<1>(a1);
    run3<1, 2, 8, 8>(a1, sW + 16384, sW + 24576, sB0h, sB0l, w, quad, l15);
#pragma unroll
    for (int s = 0; s < 4; ++s) {
      float4 v = make_float4(a1[0][s][0], a1[0][s][1], a1[0][s][2], a1[0][s][3]);
      *(float4*)&rc1pG[(size_t)((b * 8 + w) * 4 + s) * 256 + lane * 4] = v;
    }
  }
  __syncthreads();

  if (do_bases) prep_w<64, 64, TPB_E>(sW + 0, sW + 4096, an_w1, tid);
  if (do_pre)   prep_w<64, 64, TPB_E>(sW + 8192, sW + 12288, an_w1 + 64 * 64, tid);
  __syncthreads();

  if (act4) {
    if (do_bases) {
      initb<1>(a1, sb + 512, o0, quad);
      run3<1, 2, 8, 4>(a1, sW + 0, sW + 4096, sB0h, sB0l, w, quad, l15);
#pragma unroll
      for (int s = 0; s < 4; ++s) {
        float4 v = make_float4(a1[0][s][0], a1[0][s][1], a1[0][s][2], a1[0][s][3]);
        *(float4*)&baseAnG[(size_t)(b * 64 + 16 * s + l15) * 64 + o0 + quad * 4] = v;
      }
    }
    if (do_pre) {
      zeroa<1>(a1);
      run3<1, 2, 8, 4>(a1, sW + 8192, sW + 12288, sB0h, sB0l, w, quad, l15);
#pragma unroll
      for (int s = 0; s < 4; ++s) {
        float4 v = make_float4(a1[0][s][0], a1[0][s][1], a1[0][s][2], a1[0][s][3]);
        *(float4*)&an1pG[(size_t)((b * 4 + w) * 4 + s) * 256 + lane * 4] = v;
      }
    }
  }
}

// ---------------------------------------------------------------------------
// MFMA layer helper for the pair kernel (A from global blob; B from LDS).
// ---------------------------------------------------------------------------
template<int MT, int NCHUNK, int RSG, int TILES>
__device__ __forceinline__ void run_layer1(f32x4 (&acc)[MT][4],
    const u16* __restrict__ blobL,
    const u16* __restrict__ sB, int tg0, int quad, int l15) {
  const int lane = quad * 16 + l15;
#pragma unroll
  for (int c = 0; c < NCHUNK; ++c) {
    f16x8 Ah[MT];
#pragma unroll
    for (int t = 0; t < MT; ++t)
      Ah[t] = *(const f16x8*)(blobL + ((c * TILES + tg0 + t) * 64 + lane) * 8);
    const int slot = (4 * c + quad) ^ (l15 & 7);
    f16x8 Bh[4];
#pragma unroll
    for (int s = 0; s < 4; ++s)
      Bh[s] = *(const f16x8*)&sB[(16 * s + l15) * (RSG * 8) + slot * 8];
#pragma unroll
    for (int t = 0; t < MT; ++t)
#pragma unroll
      for (int s = 0; s < 4; ++s)
        acc[t][s] = __builtin_amdgcn_mfma_f32_16x16x32_f16(Ah[t], Bh[s], acc[t][s], 0, 0, 0);
  }
}

template<int MT, int RSG>
__device__ __forceinline__ void store_acts_pk(const f32x4 (&acc)[MT][4],
                                              u16* dst, int o0, int quad, int l15) {
#pragma unroll
  for (int t = 0; t < MT; ++t) {
    const int ob = o0 + 16 * t + quad * 4;
    const int slot = (ob >> 3) ^ (l15 & 7);
    const int e = ob & 7;
#pragma unroll
    for (int s = 0; s < 4; ++s) {
      const int j = 16 * s + l15;
      uint2 pk;
      pk.x = pack_f16(fmaxf(acc[t][s][0], 0.f), fmaxf(acc[t][s][1], 0.f));
      pk.y = pack_f16(fmaxf(acc[t][s][2], 0.f), fmaxf(acc[t][s][3], 0.f));
      *(uint2*)&dst[j * (RSG * 8) + slot * 8 + e] = pk;
    }
  }
}

// ---------------------------------------------------------------------------
// Kernel B (MFMA): R4 structure restored (one i per 256-thr block, 8192
// blocks, LB(256,4) — R5's 2-i/512-thr merge did NOT raise occupancy, 38.8%
// either way, and regressed 80->87.6: resident waves are pinned ~16/CU
// regardless of block geometry. DO NOT re-merge; DO NOT LB(,5) (R10 spill).
// Sigmoid is exp2-based: AN2F weights/bias pre-scaled by -log2e.
// ---------------------------------------------------------------------------
__global__ __launch_bounds__(TPB, 4) void pair_mfma_kernel(
    const u16* __restrict__ hB, const u16* __restrict__ blob,
    const float* __restrict__ baseRcG, const float* __restrict__ baseAnG,
    const float* __restrict__ rc1pG, const float* __restrict__ an1pG,
    int has_bases, int has_pre,
    const float* __restrict__ rc_w1, const float* __restrict__ rc_b1,
    const float* __restrict__ rc_b2, const float* __restrict__ rc_b3,
    const float* __restrict__ an_w1, const float* __restrict__ an_b1,
    const float* __restrict__ an_b2,
    float* __restrict__ out) {
  __shared__ __align__(16) u16 sAct[64 * 128];  // 16 KB
  __shared__ __align__(16) u16 sAn[64 * 64];    // 8 KB
  __shared__ float sHi[64], sDist[64];
  __shared__ float sBaseRc[128], sBaseAn[64], sW1d[128], sAnd[64];
  __shared__ float sB2[128], sB3[128], sAb2[128], sRed[128];

  const int tid = threadIdx.x;
  const int w = tid >> 6, lane = tid & 63;
  const int quad = lane >> 4, l15 = lane & 15;
  const int b = blockIdx.x >> 6, i = blockIdx.x & 63;
  const int o0 = w * 32;
  const int o0a = w * 16;

  f32x4 accR[2][4];
  f32x4 accN[1][4];

  if (has_pre) {
    // ======== fast path ========
    if (tid < 128) {
      sW1d[tid] = rc_w1[128 * 128 + tid];
      sB2[tid] = rc_b2[tid]; sB3[tid] = rc_b3[tid];
      sAb2[tid] = an_b2[tid] * NEG_LOG2E;
    } else if (tid < 192) {
      sAnd[tid - 128] = an_w1[128 * 64 + (tid - 128)];
    } else {
      const int j = tid - 192;
      const float hi0 = h2f(hB[(b * 64 + i) * 64 + 0]);
      const float hi1 = h2f(hB[(b * 64 + i) * 64 + 1]);
      const ushort2 hj = *(const ushort2*)&hB[(b * 64 + j) * 64];
      const float d0 = hi0 - h2f(hj.x), d1 = hi1 - h2f(hj.y);
      sDist[j] = d0 * d0 + d1 * d1;
    }
    if (tid < 32)
      ((float4*)sBaseRc)[tid] = ((const float4*)(baseRcG + (size_t)(b * 64 + i) * 128))[tid];
    else if (tid < 48)
      ((float4*)sBaseAn)[tid - 32] = ((const float4*)(baseAnG + (size_t)(b * 64 + i) * 64))[tid - 32];
    __syncthreads();

    float bbR[2][4], wwR[2][4], bbN[4], wwN[4];
#pragma unroll
    for (int t = 0; t < 2; ++t) {
      ld4(bbR[t], &sBaseRc[o0 + 16 * t + quad * 4]);
      ld4(wwR[t], &sW1d[o0 + 16 * t + quad * 4]);
    }
    ld4(bbN, &sBaseAn[o0a + quad * 4]);
    ld4(wwN, &sAnd[o0a + quad * 4]);
    const float* pR = rc1pG + (size_t)(b * 8 + 2 * w) * 1024 + lane * 4;
    const float* pA = an1pG + (size_t)(b * 4 + w) * 1024 + lane * 4;
#pragma unroll
    for (int s = 0; s < 4; ++s) {
      const float dj = sDist[16 * s + l15];
#pragma unroll
      for (int t = 0; t < 2; ++t) {
        const float4 pre = *(const float4*)(pR + t * 1024 + s * 256);
        f32x4 a;
        a[0] = pre.x + fmaf(dj, wwR[t][0], bbR[t][0]);
        a[1] = pre.y + fmaf(dj, wwR[t][1], bbR[t][1]);
        a[2] = pre.z + fmaf(dj, wwR[t][2], bbR[t][2]);
        a[3] = pre.w + fmaf(dj, wwR[t][3], bbR[t][3]);
        accR[t][s] = a;
      }
      const float4 pre = *(const float4*)(pA + s * 256);
      f32x4 a;
      a[0] = pre.x + fmaf(dj, wwN[0], bbN[0]);
      a[1] = pre.y + fmaf(dj, wwN[1], bbN[1]);
      a[2] = pre.z + fmaf(dj, wwN[2], bbN[2]);
      a[3] = pre.w + fmaf(dj, wwN[3], bbN[3]);
      accN[0][s] = a;
    }
    store_acts_pk<1, 8>(accN, sAn, o0a, quad, l15);
    store_acts_pk<2, 16>(accR, sAct, o0, quad, l15);
    __syncthreads();
  } else {
    // ======== fallback: L1 via MFMA ========
    {
      const float4* srcJ = (const float4*)(hB + b * 4096);
      for (int idx = tid; idx < 512; idx += TPB) {
        const int row = idx >> 3, g = idx & 7;
        *(float4*)&sAct[row * 128 + ((g ^ (row & 7)) * 8)] = srcJ[idx];
      }
    }
    if (has_bases) {
      const float4* bR = (const float4*)(baseRcG + (size_t)(b * 64 + i) * 128);
      const float4* bA = (const float4*)(baseAnG + (size_t)(b * 64 + i) * 64);
      if (tid < 32) ((float4*)sBaseRc)[tid] = bR[tid];
      else if (tid < 48) ((float4*)sBaseAn)[tid - 32] = bA[tid - 32];
    }
    if (tid < 64) sHi[tid] = h2f(hB[(b * 64 + i) * 64 + tid]);
    if (tid < 128) {
      sW1d[tid] = rc_w1[128 * 128 + tid];
      sB2[tid] = rc_b2[tid]; sB3[tid] = rc_b3[tid];
      sAb2[tid] = an_b2[tid] * NEG_LOG2E;
    } else if (tid < 192) {
      sAnd[tid - 128] = an_w1[128 * 64 + (tid - 128)];
    }
    __syncthreads();
    if (!has_bases) {
      if (tid < 128) {
        float acc = rc_b1[tid];
        for (int k = 0; k < 64; ++k) acc = fmaf(sHi[k], rc_w1[k * 128 + tid], acc);
        sBaseRc[tid] = acc;
      } else if (tid < 192) {
        const int o = tid - 128;
        float acc = an_b1[o];
        for (int k = 0; k < 64; ++k) acc = fmaf(sHi[k], an_w1[k * 64 + o], acc);
        sBaseAn[o] = acc;
      }
    }
    if (tid >= 192) {
      const int j = tid - 192;
      const int base = j * 128 + ((0 ^ (j & 7)) * 8);
      const float d0 = sHi[0] - h2f(sAct[base + 0]);
      const float d1 = sHi[1] - h2f(sAct[base + 1]);
      sDist[j] = d0 * d0 + d1 * d1;
    }
    __syncthreads();

    {
      float bbR[2][4], wwR[2][4], bbN[4], wwN[4];
#pragma unroll
      for (int t = 0; t < 2; ++t) {
        ld4(bbR[t], &sBaseRc[o0 + 16 * t + quad * 4]);
        ld4(wwR[t], &sW1d[o0 + 16 * t + quad * 4]);
      }
      ld4(bbN, &sBaseAn[o0a + quad * 4]);
      ld4(wwN, &sAnd[o0a + quad * 4]);
#pragma unroll
      for (int s = 0; s < 4; ++s) {
        const float dj = sDist[16 * s + l15];
#pragma unroll
        for (int t = 0; t < 2; ++t) {
          f32x4 a;
#pragma unroll
          for (int r = 0; r < 4; ++r) a[r] = fmaf(dj, wwR[t][r], bbR[t][r]);
          accR[t][s] = a;
        }
        f32x4 a;
#pragma unroll
        for (int r = 0; r < 4; ++r) a[r] = fmaf(dj, wwN[r], bbN[r]);
        accN[0][s] = a;
      }
    }
    {
      const int lane64 = quad * 16 + l15;
#pragma unroll
      for (int c = 0; c < 2; ++c) {
        f16x8 Ah[2], Al[2], AhN, AlN;
#pragma unroll
        for (int t = 0; t < 2; ++t) {
          const u16* p = blob + RC1F + ((c * 8 + 2 * w + t) * 64 + lane64) * 8;
          Ah[t] = *(const f16x8*)p;
          Al[t] = *(const f16x8*)(p + 8192);
        }
        {
          const u16* p = blob + AN1F + ((c * 4 + w) * 64 + lane64) * 8;
          AhN = *(const f16x8*)p;
          AlN = *(const f16x8*)(p + 4096);
        }
        const int slot = (4 * c + quad) ^ (l15 & 7);
        f16x8 Bh[4];
#pragma unroll
        for (int s = 0; s < 4; ++s)
          Bh[s] = *(const f16x8*)&sAct[(16 * s + l15) * 128 + slot * 8];
#pragma unroll
        for (int s = 0; s < 4; ++s) {
#pragma unroll
          for (int t = 0; t < 2; ++t) {
            f32x4 a = accR[t][s];
            a = __builtin_amdgcn_mfma_f32_16x16x32_f16(Ah[t], Bh[s], a, 0, 0, 0);
            a = __builtin_amdgcn_mfma_f32_16x16x32_f16(Al[t], Bh[s], a, 0, 0, 0);
            accR[t][s] = a;
          }
          f32x4 a = accN[0][s];
          a = __builtin_amdgcn_mfma_f32_16x16x32_f16(AhN, Bh[s], a, 0, 0, 0);
          a = __builtin_amdgcn_mfma_f32_16x16x32_f16(AlN, Bh[s], a, 0, 0, 0);
          accN[0][s] = a;
        }
      }
    }
    store_acts_pk<1, 8>(accN, sAn, o0a, quad, l15);
    __syncthreads();
    store_acts_pk<2, 16>(accR, sAct, o0, quad, l15);
    __syncthreads();
  }

  // ======== common tail: rc2 + an2 together, sigmoid, store, rc3 ========
  {
    float bb[2][4];
#pragma unroll
    for (int t = 0; t < 2; ++t) ld4(bb[t], &sB2[o0 + 16 * t + quad * 4]);
#pragma unroll
    for (int t = 0; t < 2; ++t)
#pragma unroll
      for (int s = 0; s < 4; ++s) {
        f32x4 a;
#pragma unroll
        for (int r = 0; r < 4; ++r) a[r] = bb[t][r];
        accR[t][s] = a;
      }
  }
  f32x4 accT[2][4];
  {
    float bb[2][4];
#pragma unroll
    for (int t = 0; t < 2; ++t) ld4(bb[t], &sAb2[o0 + 16 * t + quad * 4]);
#pragma unroll
    for (int t = 0; t < 2; ++t)
#pragma unroll
      for (int s = 0; s < 4; ++s) {
        f32x4 a;
#pragma unroll
        for (int r = 0; r < 4; ++r) a[r] = bb[t][r];
        accT[t][s] = a;
      }
  }
  __builtin_amdgcn_s_setprio(1);
  run_layer1<2, 4, 16, 8>(accR, blob + RC2F, sAct, 2 * w, quad, l15);
  run_layer1<2, 2, 8, 8>(accT, blob + AN2F, sAn, 2 * w, quad, l15);
  __builtin_amdgcn_s_setprio(0);
  // att = sigmoid(z) = rcp(1 + 2^(-z*log2e)); accT already = -z*log2e
  float att[2][4][4];
#pragma unroll
  for (int t = 0; t < 2; ++t)
#pragma unroll
    for (int s = 0; s < 4; ++s)
#pragma unroll
      for (int r = 0; r < 4; ++r)
        att[t][s][r] = __builtin_amdgcn_rcpf(1.0f + __builtin_amdgcn_exp2f(accT[t][s][r]));
  __syncthreads();
  store_acts_pk<2, 16>(accR, sAct, o0, quad, l15);
  __syncthreads();

  // ---- rc-L3 (init = rc_b3) + rel*att + reduce over j
  {
    float bb[2][4];
#pragma unroll
    for (int t = 0; t < 2; ++t) ld4(bb[t], &sB3[o0 + 16 * t + quad * 4]);
#pragma unroll
    for (int t = 0; t < 2; ++t)
#pragma unroll
      for (int s = 0; s < 4; ++s) {
        f32x4 a;
#pragma unroll
        for (int r = 0; r < 4; ++r) a[r] = bb[t][r];
        accR[t][s] = a;
      }
  }
  __builtin_amdgcn_s_setprio(1);
  run_layer1<2, 4, 16, 8>(accR, blob + RC3F, sAct, 2 * w, quad, l15);
  __builtin_amdgcn_s_setprio(0);
  float ps[2][4] = {{0.f, 0.f, 0.f, 0.f}, {0.f, 0.f, 0.f, 0.f}};
#pragma unroll
  for (int t = 0; t < 2; ++t)
#pragma unroll
    for (int s = 0; s < 4; ++s)
#pragma unroll
      for (int r = 0; r < 4; ++r) {
        const float rel = fmaxf(accR[t][s][r], 0.f);
        ps[t][r] = fmaf(rel, att[t][s][r], ps[t][r]);
      }
#pragma unroll
  for (int t = 0; t < 2; ++t)
#pragma unroll
    for (int r = 0; r < 4; ++r) {
      float v = ps[t][r];
      v += __shfl_xor(v, 1, 64);
      v += __shfl_xor(v, 2, 64);
      v += __shfl_xor(v, 4, 64);
      v += __shfl_xor(v, 8, 64);
      ps[t][r] = v;
    }
  if (l15 == 0) {
#pragma unroll
    for (int t = 0; t < 2; ++t)
#pragma unroll
      for (int r = 0; r < 4; ++r)
        sRed[o0 + 16 * t + quad * 4 + r] = ps[t][r];
  }
  __syncthreads();
  if (tid < 128)
    atomicAdd(&out[b * 128 + tid], sRed[tid] * (1.0f / 4096.0f));
}

extern "C" void kernel_launch(void* const* d_in, const int* in_sizes, int n_in,
                              void* d_out, int out_size, void* d_ws, size_t ws_size,
                              hipStream_t stream) {
  const float* s     = (const float*)d_in[0];
  const float* se_w1 = (const float*)d_in[1];
  const float* se_b1 = (const float*)d_in[2];
  const float* se_w2 = (const float*)d_in[3];
  const float* se_b2 = (const float*)d_in[4];
  const float* sd_w1 = (const float*)d_in[5];
  const float* sd_b1 = (const float*)d_in[6];
  const float* sd_w2 = (const float*)d_in[7];
  const float* sd_b2 = (const float*)d_in[8];
  const float* rc_w1 = (const float*)d_in[9];
  const float* rc_b1 = (const float*)d_in[10];
  const float* rc_w2 = (const float*)d_in[11];
  const float* rc_b2 = (const float*)d_in[12];
  const float* rc_w3 = (const float*)d_in[13];
  const float* rc_b3 = (const float*)d_in[14];
  const float* an_w1 = (const float*)d_in[15];
  const float* an_b1 = (const float*)d_in[16];
  const float* an_w2 = (const float*)d_in[17];
  const float* an_b2 = (const float*)d_in[18];
  float* out = (float*)d_out;
  u16* hB   = (u16*)d_ws;
  u16* blob = hB + BLOB_U16;
  float* baseRcG = (float*)d_ws + BASE_RC_F32;
  float* baseAnG = (float*)d_ws + BASE_AN_F32;
  float* rc1pG   = (float*)d_ws + RC1P_F32;
  float* an1pG   = (float*)d_ws + AN1P_F32;
  const int has_pre   = (ws_size >= WS_NEED_PRE) ? 1 : 0;
  const int has_bases = (ws_size >= WS_NEED_BASES) ? 1 : 0;
  (void)n_in; (void)in_sizes; (void)out_size;

  enc_prep_kernel<<<FUSED_BLOCKS, TPB_E, 0, stream>>>(s, se_w1, se_b1, se_w2, se_b2,
                                           sd_w1, sd_b1, sd_w2, sd_b2,
                                           rc_w1, rc_b1, rc_w2, rc_w3,
                                           an_w1, an_b1, an_w2,
                                           hB, blob, baseRcG, baseAnG, rc1pG, an1pG,
                                           has_bases, has_pre, out);
  pair_mfma_kernel<<<8192, TPB, 0, stream>>>(hB, blob, baseRcG, baseAnG, rc1pG, an1pG,
                                             has_bases, has_pre,
                                             rc_w1, rc_b1, rc_b2, rc_b3,
                                             an_w1, an_b1, an_b2, out);
}